// Round 4
// baseline (605.082 us; speedup 1.0000x reference)
//
#include <hip/hip_runtime.h>
#include <hip/hip_bf16.h>

// LSTMEncoder: B=65536, T=25, I=4, H=64, 2 layers, out = h2 at t=4,9,14,19,24.
// Split-precision matmul (v = hi + lo bf16 pairs) for f32-accurate trajectory:
//   h@W ~= h_hi@W_hi + h_hi@W_lo + h_lo@W_hi  (exact products, f32 MFMA acc)
// Elementwise pure f32 (hw exp2/rcp).
//
// R7:  wave specialization (waves 0-3 = layer 1, 4-7 = layer 2).
// R8:  pre-split weights into d_ws (killed per-iter splitf remat).
// R9/R10: LDS squeeze proved 2 blocks/CU fits LDS, but weights (~208 regs of
//   fragments per SIMD across the L1+L2 pair, held in the unified VGPR/AGPR
//   file at ~256 total/wave) make 4 waves/SIMD impossible without spill.
//   Occupancy is structurally capped at 2 waves/SIMD. R10: 575us,
//   VALUBusy 55 + MfmaUtil 40 ~= 95 = SUM -> pipes serialize: both waves
//   start MFMA together after each barrier, collide on the matrix pipe,
//   then collide on the VALU pipe.
// R11 (this round): ANTI-PHASE SCHEDULING at constant occupancy. L2's
//   pipeline is rotated by one mt-tile: each iteration it leads with the
//   ELEMENTWISE of the previous timestep's mt3 (zs carried in 16 regs across
//   the barrier), then [mfma;ew] mt0..2, ending with mfma(mt3) kept. L1
//   leads with mfma(mt0). Post-barrier: L1 on MFMA pipe, L2 on VALU pipe,
//   alternating in opposite phase. A 2nd (mid) barrier per iter is required:
//   rotated ew(mt3,t2-1) writes H2 rows 48-63 that all L2 waves' mfma(mt3,t2)
//   read later the same iteration. sched_barrier(0) pins burst boundaries;
//   setprio(1) wraps MFMA clusters (T5 pays once waves are phase-split).
//   L2 bias splats (16 regs) -> 4 scalars to offset the carried zs.
//
// MFMA 16x16x32 bf16 layouts (measured, learn_hip m89/m120):
//   A[m][k]: m=lane&15, k=(lane>>4)*8+e ; B[k][n]: n=lane&15, k=(lane>>4)*8+e
//   C/D    : col=lane&15, row=(lane>>4)*4+reg

typedef short short8 __attribute__((ext_vector_type(8)));
typedef float floatx4 __attribute__((ext_vector_type(4)));

namespace {
constexpr int T_ = 25;
constexpr int I_ = 4;
constexpr int MB = 64;     // batch rows per block
constexpr int HSTR = 72;   // LDS row stride (shorts): 144B, 16B-aligned, 2-way banks
constexpr int XSTR = 24;   // x tile stride (shorts): 48B, 2-way banks
constexpr int XPAD = 8;    // last-row overread pad (q=3 reads offs 24..31)

// Workspace layout, in short8 (16B fragment-row) units.
constexpr int OFF_BX   = 0;
constexpr int OFF_HH0H = 1024;
constexpr int OFF_HH0L = 3072;
constexpr int OFF_IH1H = 5120;
constexpr int OFF_IH1L = 7168;
constexpr int OFF_HH1H = 9216;
constexpr int OFF_HH1L = 11264;
}

__device__ __forceinline__ float sigm_(float x) {
  float t = __builtin_amdgcn_exp2f(x * -1.44269504088896340736f);  // e^-x
  return __builtin_amdgcn_rcpf(1.0f + t);
}
__device__ __forceinline__ float tanh_(float x) {
  float t = __builtin_amdgcn_exp2f(x * -2.88539008177792681472f);  // e^-2x
  return 2.0f * __builtin_amdgcn_rcpf(1.0f + t) - 1.0f;
}
__device__ __forceinline__ unsigned short f2bf_(float f) {  // RNE f32->bf16
  unsigned u = __float_as_uint(f);
  u += 0x7FFFu + ((u >> 16) & 1u);
  return (unsigned short)(u >> 16);
}
__device__ __forceinline__ float bf2f_(unsigned short s) {
  return __uint_as_float(((unsigned)s) << 16);
}
__device__ __forceinline__ void splitf_(float f, unsigned short& hi, unsigned short& lo) {
  hi = f2bf_(f);
  lo = f2bf_(f - bf2f_(hi));
}

// ---------------------------------------------------------------------------
// Prep kernel: split weights once into fragment-ordered hi/lo short8 rows.
// ---------------------------------------------------------------------------
__global__ void prep_weights(const float* __restrict__ Wih0,   // [256,4]
                             const float* __restrict__ Whh0,   // [256,64]
                             const float* __restrict__ Wih1,   // [256,64]
                             const float* __restrict__ Whh1,   // [256,64]
                             unsigned short* __restrict__ ws) {
  const int t = blockIdx.x * 256 + threadIdx.x;
  if (t < 1024) {
    const int lane = t & 63, w = (t >> 6) & 3, g = t >> 8;
    const int l = lane & 15, q = lane >> 4;
    const int n = g * 64 + w * 16 + l;
    unsigned short row[8];
#pragma unroll
    for (int e = 0; e < 8; ++e) row[e] = 0;
    if (q < 2) {
#pragma unroll
      for (int e = 0; e < 4; ++e) {
        unsigned short h, lo;
        splitf_(Wih0[n * 4 + e], h, lo);
        row[e] = h;
        if (q == 0) row[4 + e] = lo;
      }
    }
#pragma unroll
    for (int e = 0; e < 8; ++e) ws[(OFF_BX + t) * 8 + e] = row[e];
  } else if (t < 7168) {
    const int a = (t - 1024) >> 11;    // 0:Whh0 1:Wih1 2:Whh1
    const int r = (t - 1024) & 2047;   // r = g*512 + hf*256 + w*64 + lane
    const int lane = r & 63, w = (r >> 6) & 3, hf = (r >> 8) & 1, g = r >> 9;
    const int l = lane & 15, q = lane >> 4;
    const int n = g * 64 + w * 16 + l;
    const float* src = (a == 0) ? Whh0 : (a == 1) ? Wih1 : Whh1;
    const int offH = (a == 0) ? OFF_HH0H : (a == 1) ? OFF_IH1H : OFF_HH1H;
    const int offL = offH + 2048;
#pragma unroll
    for (int e = 0; e < 8; ++e) {
      unsigned short h, lo;
      splitf_(src[n * 64 + hf * 32 + q * 8 + e], h, lo);
      ws[(offH + r) * 8 + e] = h;
      ws[(offL + r) * 8 + e] = lo;
    }
  }
}

// ---------------------------------------------------------------------------
// Main kernel
// ---------------------------------------------------------------------------
__global__ __launch_bounds__(512, 2)
void lstm2_kernel(const float* __restrict__ x,     // [B,25,4]
                  const float* __restrict__ b0,    // [256]
                  const float* __restrict__ b1,    // [256]
                  const short8* __restrict__ wf,   // pre-split weight frags
                  float* __restrict__ out) {       // [B,5,64]
  __shared__ __align__(16) unsigned short H1h[2][MB * HSTR];
  __shared__ __align__(16) unsigned short H1l[2][MB * HSTR];
  __shared__ __align__(16) unsigned short H2h[2][MB * HSTR];
  __shared__ __align__(16) unsigned short H2l[2][MB * HSTR];
  __shared__ __align__(16) unsigned short XB[2][MB * XSTR + XPAD];

  const int tid = threadIdx.x;
  const int lane = tid & 63;
  const int w = tid >> 6;   // 0..7
  const int l = lane & 15;
  const int q = lane >> 4;
  const int mbase = blockIdx.x * MB;

  // ---- init LDS: zero the [1] state buffers (h(-1)=0) + both XB buffers ----
  for (int idx = tid; idx < MB * 64; idx += 512) {
    int m = idx >> 6, k = idx & 63;
    H1h[1][m * HSTR + k] = 0;
    H1l[1][m * HSTR + k] = 0;
    H2h[1][m * HSTR + k] = 0;
    H2l[1][m * HSTR + k] = 0;
  }
  for (int idx = tid; idx < 2 * (MB * XSTR + XPAD); idx += 512) (&XB[0][0])[idx] = 0;
  if (tid < 256) {  // stage x(0) into XB[0]
    int m = tid >> 2, ii = tid & 3;
    unsigned short xh, xl;
    splitf_(x[(mbase + m) * (T_ * I_) + ii], xh, xl);
    XB[0][m * XSTR + ii] = xh;
    XB[0][m * XSTR + 4 + ii] = xh;
    XB[0][m * XSTR + 8 + ii] = xl;
  }
  __syncthreads();

  if (w < 4) {
    // ==================== LAYER-1 WAVES (0..3) ====================
    const int j = w * 16 + l;  // hidden col owned (all 4 gates)
    short8 B1h[4][2], B1l[4][2], BXf[4];
    floatx4 bias0v[4];
#pragma unroll
    for (int g = 0; g < 4; ++g) {
      BXf[g] = wf[OFF_BX + g * 256 + w * 64 + lane];
#pragma unroll
      for (int hf = 0; hf < 2; ++hf) {
        B1h[g][hf] = wf[OFF_HH0H + (g * 2 + hf) * 256 + w * 64 + lane];
        B1l[g][hf] = wf[OFF_HH0L + (g * 2 + hf) * 256 + w * 64 + lane];
      }
      float bb = b0[g * 64 + j];
      bias0v[g] = (floatx4){bb, bb, bb, bb};
    }
    float c1[16];
#pragma unroll
    for (int k = 0; k < 16; ++k) c1[k] = 0.f;
    floatx4 zs[4];

#define L1_MFMA(mt_, p_)                                                      \
  {                                                                           \
    const int row_ = (mt_) * 16 + l;                                          \
    short8 a0h = *(const short8*)&H1h[(p_) ^ 1][row_ * HSTR + q * 8];         \
    short8 a1h = *(const short8*)&H1h[(p_) ^ 1][row_ * HSTR + 32 + q * 8];    \
    short8 a0l = *(const short8*)&H1l[(p_) ^ 1][row_ * HSTR + q * 8];         \
    short8 a1l = *(const short8*)&H1l[(p_) ^ 1][row_ * HSTR + 32 + q * 8];    \
    short8 ax  = *(const short8*)&XB[p_][row_ * XSTR + q * 8];                \
    __builtin_amdgcn_s_setprio(1);                                            \
    _Pragma("unroll")                                                         \
    for (int g = 0; g < 4; ++g) {                                             \
      floatx4 a_ = bias0v[g];                                                 \
      a_ = __builtin_amdgcn_mfma_f32_16x16x32_bf16(ax,  BXf[g],    a_, 0, 0, 0); \
      a_ = __builtin_amdgcn_mfma_f32_16x16x32_bf16(a0h, B1h[g][0], a_, 0, 0, 0); \
      a_ = __builtin_amdgcn_mfma_f32_16x16x32_bf16(a1h, B1h[g][1], a_, 0, 0, 0); \
      a_ = __builtin_amdgcn_mfma_f32_16x16x32_bf16(a0h, B1l[g][0], a_, 0, 0, 0); \
      a_ = __builtin_amdgcn_mfma_f32_16x16x32_bf16(a1h, B1l[g][1], a_, 0, 0, 0); \
      a_ = __builtin_amdgcn_mfma_f32_16x16x32_bf16(a0l, B1h[g][0], a_, 0, 0, 0); \
      a_ = __builtin_amdgcn_mfma_f32_16x16x32_bf16(a1l, B1h[g][1], a_, 0, 0, 0); \
      zs[g] = a_;                                                             \
    }                                                                         \
    __builtin_amdgcn_s_setprio(0);                                            \
  }

#define L1_EW(mt_, p_)                                                        \
  {                                                                           \
    _Pragma("unroll")                                                         \
    for (int r = 0; r < 4; ++r) {                                             \
      float si = sigm_(zs[0][r]);                                             \
      float sf = sigm_(zs[1][r]);                                             \
      float tg = tanh_(zs[2][r]);                                             \
      float so = sigm_(zs[3][r]);                                             \
      float cc = sf * c1[(mt_) * 4 + r] + si * tg;                            \
      c1[(mt_) * 4 + r] = cc;                                                 \
      float h = so * tanh_(cc);                                               \
      unsigned short hh, hl;                                                  \
      splitf_(h, hh, hl);                                                     \
      const int m_ = (mt_) * 16 + q * 4 + r;                                  \
      H1h[p_][m_ * HSTR + j] = hh;                                            \
      H1l[p_][m_ * HSTR + j] = hl;                                            \
    }                                                                         \
  }

#pragma unroll 1
    for (int k = 0; k < T_ + 2; ++k) {
      const bool act = (k < T_);
      const int p = k & 1;
      if (act) {
        L1_MFMA(0, p)                       // pre-mid: MFMA burst (anti-phase vs L2 ew)
      }
      __syncthreads();                      // BAR-MID
      if (act) {
        L1_EW(0, p)
        __builtin_amdgcn_sched_barrier(0);
        L1_MFMA(1, p)
        __builtin_amdgcn_sched_barrier(0);
        L1_EW(1, p)
        __builtin_amdgcn_sched_barrier(0);
        L1_MFMA(2, p)
        __builtin_amdgcn_sched_barrier(0);
        L1_EW(2, p)
        __builtin_amdgcn_sched_barrier(0);
        L1_MFMA(3, p)
        __builtin_amdgcn_sched_barrier(0);
        L1_EW(3, p)
        if (k + 1 < T_) {  // stage x(k+1) into the other XB buffer
          int m = (tid & 255) >> 2, ii = tid & 3;
          unsigned short xh, xl;
          splitf_(x[(mbase + m) * (T_ * I_) + (k + 1) * I_ + ii], xh, xl);
          XB[(k + 1) & 1][m * XSTR + ii] = xh;
          XB[(k + 1) & 1][m * XSTR + 4 + ii] = xh;
          XB[(k + 1) & 1][m * XSTR + 8 + ii] = xl;
        }
      }
      __syncthreads();                      // BAR-END
    }
#undef L1_MFMA
#undef L1_EW
  } else {
    // ==================== LAYER-2 WAVES (4..7) ====================
    const int w2 = w - 4;
    const int j = w2 * 16 + l;
    short8 B2h[4][4], B2l[4][4];  // [0..1]=Wih1, [2..3]=Whh1
    float bias1s[4];
#pragma unroll
    for (int g = 0; g < 4; ++g) {
#pragma unroll
      for (int hf = 0; hf < 2; ++hf) {
        B2h[g][hf]     = wf[OFF_IH1H + (g * 2 + hf) * 256 + w2 * 64 + lane];
        B2l[g][hf]     = wf[OFF_IH1L + (g * 2 + hf) * 256 + w2 * 64 + lane];
        B2h[g][2 + hf] = wf[OFF_HH1H + (g * 2 + hf) * 256 + w2 * 64 + lane];
        B2l[g][2 + hf] = wf[OFF_HH1L + (g * 2 + hf) * 256 + w2 * 64 + lane];
      }
      bias1s[g] = b1[g * 64 + j];
    }
    float c2[16];
#pragma unroll
    for (int k = 0; k < 16; ++k) c2[k] = 0.f;
    floatx4 zs3[4];  // mt3 accumulators, carried across BAR-END
    floatx4 zsB[4];  // mt0..2 transient accumulators

#define L2_MFMA(mt_, t2_, zsp_)                                               \
  {                                                                           \
    const int p2_ = (t2_) & 1;                                                \
    const int row_ = (mt_) * 16 + l;                                          \
    short8 n0h = *(const short8*)&H1h[p2_][row_ * HSTR + q * 8];              \
    short8 n1h = *(const short8*)&H1h[p2_][row_ * HSTR + 32 + q * 8];         \
    short8 n0l = *(const short8*)&H1l[p2_][row_ * HSTR + q * 8];              \
    short8 n1l = *(const short8*)&H1l[p2_][row_ * HSTR + 32 + q * 8];         \
    short8 m0h = *(const short8*)&H2h[p2_ ^ 1][row_ * HSTR + q * 8];          \
    short8 m1h = *(const short8*)&H2h[p2_ ^ 1][row_ * HSTR + 32 + q * 8];     \
    short8 m0l = *(const short8*)&H2l[p2_ ^ 1][row_ * HSTR + q * 8];          \
    short8 m1l = *(const short8*)&H2l[p2_ ^ 1][row_ * HSTR + 32 + q * 8];     \
    __builtin_amdgcn_s_setprio(1);                                            \
    _Pragma("unroll")                                                         \
    for (int g = 0; g < 4; ++g) {                                             \
      floatx4 a_ = (floatx4){bias1s[g], bias1s[g], bias1s[g], bias1s[g]};     \
      a_ = __builtin_amdgcn_mfma_f32_16x16x32_bf16(n0h, B2h[g][0], a_, 0, 0, 0); \
      a_ = __builtin_amdgcn_mfma_f32_16x16x32_bf16(n1h, B2h[g][1], a_, 0, 0, 0); \
      a_ = __builtin_amdgcn_mfma_f32_16x16x32_bf16(n0h, B2l[g][0], a_, 0, 0, 0); \
      a_ = __builtin_amdgcn_mfma_f32_16x16x32_bf16(n1h, B2l[g][1], a_, 0, 0, 0); \
      a_ = __builtin_amdgcn_mfma_f32_16x16x32_bf16(n0l, B2h[g][0], a_, 0, 0, 0); \
      a_ = __builtin_amdgcn_mfma_f32_16x16x32_bf16(n1l, B2h[g][1], a_, 0, 0, 0); \
      a_ = __builtin_amdgcn_mfma_f32_16x16x32_bf16(m0h, B2h[g][2], a_, 0, 0, 0); \
      a_ = __builtin_amdgcn_mfma_f32_16x16x32_bf16(m1h, B2h[g][3], a_, 0, 0, 0); \
      a_ = __builtin_amdgcn_mfma_f32_16x16x32_bf16(m0h, B2l[g][2], a_, 0, 0, 0); \
      a_ = __builtin_amdgcn_mfma_f32_16x16x32_bf16(m1h, B2l[g][3], a_, 0, 0, 0); \
      a_ = __builtin_amdgcn_mfma_f32_16x16x32_bf16(m0l, B2h[g][2], a_, 0, 0, 0); \
      a_ = __builtin_amdgcn_mfma_f32_16x16x32_bf16(m1l, B2h[g][3], a_, 0, 0, 0); \
      (zsp_)[g] = a_;                                                         \
    }                                                                         \
    __builtin_amdgcn_s_setprio(0);                                            \
  }

#define L2_EW(mt_, t2_, zsp_)                                                 \
  {                                                                           \
    const int p2_ = (t2_) & 1;                                                \
    const bool do_out_ = ((t2_) % 5 == 4);                                    \
    const int kk_ = (t2_) / 5;                                                \
    _Pragma("unroll")                                                         \
    for (int r = 0; r < 4; ++r) {                                             \
      float si = sigm_((zsp_)[0][r]);                                         \
      float sf = sigm_((zsp_)[1][r]);                                         \
      float tg = tanh_((zsp_)[2][r]);                                         \
      float so = sigm_((zsp_)[3][r]);                                         \
      float cc = sf * c2[(mt_) * 4 + r] + si * tg;                            \
      c2[(mt_) * 4 + r] = cc;                                                 \
      float h = so * tanh_(cc);                                               \
      unsigned short hh, hl;                                                  \
      splitf_(h, hh, hl);                                                     \
      const int m_ = (mt_) * 16 + q * 4 + r;                                  \
      H2h[p2_][m_ * HSTR + j] = hh;                                           \
      H2l[p2_][m_ * HSTR + j] = hl;                                           \
      if (do_out_) out[(size_t)(mbase + m_) * 320 + (size_t)kk_ * 64 + j] = h;\
    }                                                                         \
  }

#pragma unroll 1
    for (int k = 0; k < T_ + 2; ++k) {
      const bool rot = (k >= 2);             // rotated ew(mt3, t2=k-2), k-2 in [0,24]
      const bool act = (k >= 1 && k <= T_);  // mfma/ew(t2=k-1), k-1 in [0,24]
      if (rot) {
        L2_EW(3, k - 2, zs3)                 // pre-mid: VALU burst (anti-phase vs L1 mfma)
      }
      __syncthreads();                       // BAR-MID
      if (act) {
        const int t2 = k - 1;
        L2_MFMA(0, t2, zsB)
        __builtin_amdgcn_sched_barrier(0);
        L2_EW(0, t2, zsB)
        __builtin_amdgcn_sched_barrier(0);
        L2_MFMA(1, t2, zsB)
        __builtin_amdgcn_sched_barrier(0);
        L2_EW(1, t2, zsB)
        __builtin_amdgcn_sched_barrier(0);
        L2_MFMA(2, t2, zsB)
        __builtin_amdgcn_sched_barrier(0);
        L2_EW(2, t2, zsB)
        __builtin_amdgcn_sched_barrier(0);
        L2_MFMA(3, t2, zs3)                  // kept across BAR-END for next iter's rotated ew
      }
      __syncthreads();                       // BAR-END
    }
#undef L2_MFMA
#undef L2_EW
  }
}

extern "C" void kernel_launch(void* const* d_in, const int* in_sizes, int n_in,
                              void* d_out, int out_size, void* d_ws, size_t ws_size,
                              hipStream_t stream) {
  const float* xp   = (const float*)d_in[0];
  const float* Wih0 = (const float*)d_in[1];
  const float* Whh0 = (const float*)d_in[2];
  const float* b0   = (const float*)d_in[3];
  const float* Wih1 = (const float*)d_in[4];
  const float* Whh1 = (const float*)d_in[5];
  const float* b1   = (const float*)d_in[6];
  float* outp = (float*)d_out;
  unsigned short* ws = (unsigned short*)d_ws;

  // Pre-split weights into fragment-ordered hi/lo arrays (212992 B of d_ws).
  hipLaunchKernelGGL(prep_weights, dim3(28), dim3(256), 0, stream,
                     Wih0, Whh0, Wih1, Whh1, ws);

  const int B = in_sizes[0] / (T_ * I_);  // 65536
  dim3 grid(B / MB), block(512);
  hipLaunchKernelGGL(lstm2_kernel, grid, block, 0, stream,
                     xp, b0, b1, (const short8*)ws, outp);
}

// Round 5
// 583.937 us; speedup vs baseline: 1.0362x; 1.0362x over previous
//
#include <hip/hip_runtime.h>
#include <hip/hip_bf16.h>

// LSTMEncoder: B=65536, T=25, I=4, H=64, 2 layers, out = h2 at t=4,9,14,19,24.
// Split-precision matmul (v = hi + lo bf16 pairs) for f32-accurate trajectory:
//   h@W ~= h_hi@W_hi + h_hi@W_lo + h_lo@W_hi  (exact products, f32 MFMA acc)
// Elementwise pure f32 (hw exp2/rcp).
//
// R7:  wave specialization (waves 0-3 = layer 1, 4-7 = layer 2), 1 barrier/iter.
// R8:  pre-split weights into d_ws (killed per-iter splitf remat).
// R9/R10: LDS squeeze; occupancy structurally capped at 2 waves/SIMD by
//   register-resident weights (~208 regs/SIMD across the L1+L2 wave pair).
// R11: anti-phase scheduling (2 barriers/iter + rotation + setprio): ZERO
//   counter delta vs R10 -> pipe collision was NOT the bottleneck. Reverted.
// R12 (this round): CUT ELEMENTWISE VALU WORK. VALU/trans pipe is the
//   dominant per-SIMD workload (VALUBusy 56 > MfmaUtil 40; ~4k VALU cycles
//   vs ~1.5k MFMA cycles per SIMD-iter). Three exact/2nd-order cuts:
//   (a) activation input scales folded into pre-split weights+biases
//       (i,f,o rows x -log2e; g rows x -2log2e) -> sigma = rcp(1+exp2(z)),
//       no per-activation mul;
//   (b) truncation-split for h: hi = u&0xffff0000, lo = h-hi, stores are
//       (u>>16)/(ulo>>16) -> ds_write_b16_d16_hi; replaces 10-op RNE splitf.
//       hi+lo still = h to ~2^-16 rel (lo absorbs hi's truncation exactly);
//   (c) single-barrier R10 loop, no setprio/sched_barrier (measured dead).
//
// MFMA 16x16x32 bf16 layouts (measured, learn_hip m89/m120):
//   A[m][k]: m=lane&15, k=(lane>>4)*8+e ; B[k][n]: n=lane&15, k=(lane>>4)*8+e
//   C/D    : col=lane&15, row=(lane>>4)*4+reg

typedef short short8 __attribute__((ext_vector_type(8)));
typedef float floatx4 __attribute__((ext_vector_type(4)));

namespace {
constexpr int T_ = 25;
constexpr int I_ = 4;
constexpr int MB = 64;     // batch rows per block
constexpr int HSTR = 72;   // LDS row stride (shorts): 144B, 16B-aligned, 2-way banks
constexpr int XSTR = 24;   // x tile stride (shorts): 48B, 2-way banks
constexpr int XPAD = 8;    // last-row overread pad (q=3 reads offs 24..31)

// Workspace layout, in short8 (16B fragment-row) units.
constexpr int OFF_BX   = 0;
constexpr int OFF_HH0H = 1024;
constexpr int OFF_HH0L = 3072;
constexpr int OFF_IH1H = 5120;
constexpr int OFF_IH1L = 7168;
constexpr int OFF_HH1H = 9216;
constexpr int OFF_HH1L = 11264;

constexpr float SC_SIG  = -1.44269504088896340736f;  // -log2(e)
constexpr float SC_TANH = -2.88539008177792681472f;  // -2*log2(e)
}

// Activation helpers. Inputs of sigm2_/tanhg_ are PRE-SCALED via the weights.
__device__ __forceinline__ float sigm2_(float z) {   // z = -log2e * x
  float t = __builtin_amdgcn_exp2f(z);
  return __builtin_amdgcn_rcpf(1.0f + t);
}
__device__ __forceinline__ float tanhg_(float z) {   // z = -2*log2e * x
  float t = __builtin_amdgcn_exp2f(z);
  return 2.0f * __builtin_amdgcn_rcpf(1.0f + t) - 1.0f;
}
__device__ __forceinline__ float tanhc_(float x) {   // plain tanh (c is unscaled)
  float t = __builtin_amdgcn_exp2f(x * SC_TANH);
  return 2.0f * __builtin_amdgcn_rcpf(1.0f + t) - 1.0f;
}

__device__ __forceinline__ unsigned short f2bf_(float f) {  // RNE f32->bf16 (prep only)
  unsigned u = __float_as_uint(f);
  u += 0x7FFFu + ((u >> 16) & 1u);
  return (unsigned short)(u >> 16);
}
__device__ __forceinline__ float bf2f_(unsigned short s) {
  return __uint_as_float(((unsigned)s) << 16);
}
__device__ __forceinline__ void splitf_(float f, unsigned short& hi, unsigned short& lo) {
  hi = f2bf_(f);
  lo = f2bf_(f - bf2f_(hi));
}

// ---------------------------------------------------------------------------
// Prep kernel: scale by activation constants, then split into fragment-ordered
// hi/lo short8 rows. Runs once; RNE split kept here (free).
// ---------------------------------------------------------------------------
__global__ void prep_weights(const float* __restrict__ Wih0,   // [256,4]
                             const float* __restrict__ Whh0,   // [256,64]
                             const float* __restrict__ Wih1,   // [256,64]
                             const float* __restrict__ Whh1,   // [256,64]
                             unsigned short* __restrict__ ws) {
  const int t = blockIdx.x * 256 + threadIdx.x;
  if (t < 1024) {
    const int lane = t & 63, w = (t >> 6) & 3, g = t >> 8;
    const int l = lane & 15, q = lane >> 4;
    const int n = g * 64 + w * 16 + l;
    const float sc = (g == 2) ? SC_TANH : SC_SIG;
    unsigned short row[8];
#pragma unroll
    for (int e = 0; e < 8; ++e) row[e] = 0;
    if (q < 2) {
#pragma unroll
      for (int e = 0; e < 4; ++e) {
        unsigned short h, lo;
        splitf_(Wih0[n * 4 + e] * sc, h, lo);
        row[e] = h;
        if (q == 0) row[4 + e] = lo;
      }
    }
#pragma unroll
    for (int e = 0; e < 8; ++e) ws[(OFF_BX + t) * 8 + e] = row[e];
  } else if (t < 7168) {
    const int a = (t - 1024) >> 11;    // 0:Whh0 1:Wih1 2:Whh1
    const int r = (t - 1024) & 2047;   // r = g*512 + hf*256 + w*64 + lane
    const int lane = r & 63, w = (r >> 6) & 3, hf = (r >> 8) & 1, g = r >> 9;
    const int l = lane & 15, q = lane >> 4;
    const int n = g * 64 + w * 16 + l;
    const float sc = (g == 2) ? SC_TANH : SC_SIG;
    const float* src = (a == 0) ? Whh0 : (a == 1) ? Wih1 : Whh1;
    const int offH = (a == 0) ? OFF_HH0H : (a == 1) ? OFF_IH1H : OFF_HH1H;
    const int offL = offH + 2048;
#pragma unroll
    for (int e = 0; e < 8; ++e) {
      unsigned short h, lo;
      splitf_(src[n * 64 + hf * 32 + q * 8 + e] * sc, h, lo);
      ws[(offH + r) * 8 + e] = h;
      ws[(offL + r) * 8 + e] = lo;
    }
  }
}

// ---------------------------------------------------------------------------
// Main kernel
// ---------------------------------------------------------------------------
__global__ __launch_bounds__(512, 2)
void lstm2_kernel(const float* __restrict__ x,     // [B,25,4]
                  const float* __restrict__ b0,    // [256]
                  const float* __restrict__ b1,    // [256]
                  const short8* __restrict__ wf,   // pre-split scaled weight frags
                  float* __restrict__ out) {       // [B,5,64]
  // h1(t) lives in H1*[t&1]; h2(t) in H2*[t&1]; x(t) in XB[t&1].
  __shared__ __align__(16) unsigned short H1h[2][MB * HSTR];
  __shared__ __align__(16) unsigned short H1l[2][MB * HSTR];
  __shared__ __align__(16) unsigned short H2h[2][MB * HSTR];
  __shared__ __align__(16) unsigned short H2l[2][MB * HSTR];
  __shared__ __align__(16) unsigned short XB[2][MB * XSTR + XPAD];

  const int tid = threadIdx.x;
  const int lane = tid & 63;
  const int w = tid >> 6;   // 0..7
  const int l = lane & 15;
  const int q = lane >> 4;
  const int mbase = blockIdx.x * MB;

  // ---- init LDS: zero the [1] state buffers (h(-1)=0) + both XB buffers ----
  for (int idx = tid; idx < MB * 64; idx += 512) {
    int m = idx >> 6, k = idx & 63;
    H1h[1][m * HSTR + k] = 0;
    H1l[1][m * HSTR + k] = 0;
    H2h[1][m * HSTR + k] = 0;
    H2l[1][m * HSTR + k] = 0;
  }
  for (int idx = tid; idx < 2 * (MB * XSTR + XPAD); idx += 512) (&XB[0][0])[idx] = 0;
  if (tid < 256) {  // stage x(0) into XB[0] (truncation split)
    int m = tid >> 2, ii = tid & 3;
    float xv = x[(mbase + m) * (T_ * I_) + ii];
    unsigned u = __float_as_uint(xv);
    float hif = __uint_as_float(u & 0xffff0000u);
    unsigned ul = __float_as_uint(xv - hif);
    XB[0][m * XSTR + ii] = (unsigned short)(u >> 16);
    XB[0][m * XSTR + 4 + ii] = (unsigned short)(u >> 16);
    XB[0][m * XSTR + 8 + ii] = (unsigned short)(ul >> 16);
  }
  __syncthreads();

  if (w < 4) {
    // ==================== LAYER-1 WAVES (0..3) ====================
    const int j = w * 16 + l;  // hidden col owned (all 4 gates)
    short8 B1h[4][2], B1l[4][2], BXf[4];
    floatx4 bias0v[4];
#pragma unroll
    for (int g = 0; g < 4; ++g) {
      BXf[g] = wf[OFF_BX + g * 256 + w * 64 + lane];
#pragma unroll
      for (int hf = 0; hf < 2; ++hf) {
        B1h[g][hf] = wf[OFF_HH0H + (g * 2 + hf) * 256 + w * 64 + lane];
        B1l[g][hf] = wf[OFF_HH0L + (g * 2 + hf) * 256 + w * 64 + lane];
      }
      float bb = b0[g * 64 + j] * ((g == 2) ? SC_TANH : SC_SIG);
      bias0v[g] = (floatx4){bb, bb, bb, bb};
    }
    float c1[16];
#pragma unroll
    for (int k = 0; k < 16; ++k) c1[k] = 0.f;

#pragma unroll 1
    for (int tt = 0; tt < T_ + 1; ++tt) {
      if (tt < T_) {
        const int p = tt & 1;  // write h1(tt) -> H1*[p]; read h1(tt-1) <- H1*[p^1]
#pragma unroll
        for (int mt = 0; mt < 4; ++mt) {
          const int row = mt * 16 + l;
          short8 a0h = *(const short8*)&H1h[p ^ 1][row * HSTR + q * 8];
          short8 a1h = *(const short8*)&H1h[p ^ 1][row * HSTR + 32 + q * 8];
          short8 a0l = *(const short8*)&H1l[p ^ 1][row * HSTR + q * 8];
          short8 a1l = *(const short8*)&H1l[p ^ 1][row * HSTR + 32 + q * 8];
          short8 ax  = *(const short8*)&XB[p][row * XSTR + q * 8];
          floatx4 zs[4];
#pragma unroll
          for (int g = 0; g < 4; ++g) {
            floatx4 a_ = bias0v[g];
            a_ = __builtin_amdgcn_mfma_f32_16x16x32_bf16(ax,  BXf[g],    a_, 0, 0, 0);
            a_ = __builtin_amdgcn_mfma_f32_16x16x32_bf16(a0h, B1h[g][0], a_, 0, 0, 0);
            a_ = __builtin_amdgcn_mfma_f32_16x16x32_bf16(a1h, B1h[g][1], a_, 0, 0, 0);
            a_ = __builtin_amdgcn_mfma_f32_16x16x32_bf16(a0h, B1l[g][0], a_, 0, 0, 0);
            a_ = __builtin_amdgcn_mfma_f32_16x16x32_bf16(a1h, B1l[g][1], a_, 0, 0, 0);
            a_ = __builtin_amdgcn_mfma_f32_16x16x32_bf16(a0l, B1h[g][0], a_, 0, 0, 0);
            a_ = __builtin_amdgcn_mfma_f32_16x16x32_bf16(a1l, B1h[g][1], a_, 0, 0, 0);
            zs[g] = a_;
          }
#pragma unroll
          for (int r = 0; r < 4; ++r) {
            float si = sigm2_(zs[0][r]);
            float sf = sigm2_(zs[1][r]);
            float tg = tanhg_(zs[2][r]);
            float so = sigm2_(zs[3][r]);
            float cc = sf * c1[mt * 4 + r] + si * tg;
            c1[mt * 4 + r] = cc;
            float h = so * tanhc_(cc);
            unsigned u = __float_as_uint(h);
            float hif = __uint_as_float(u & 0xffff0000u);
            unsigned ul = __float_as_uint(h - hif);
            const int m = mt * 16 + q * 4 + r;
            H1h[p][m * HSTR + j] = (unsigned short)(u >> 16);
            H1l[p][m * HSTR + j] = (unsigned short)(ul >> 16);
          }
        }
        if (tt + 1 < T_) {  // stage x(tt+1) into the other XB buffer
          int m = (tid & 255) >> 2, ii = tid & 3;
          float xv = x[(mbase + m) * (T_ * I_) + (tt + 1) * I_ + ii];
          unsigned u = __float_as_uint(xv);
          float hif = __uint_as_float(u & 0xffff0000u);
          unsigned ul = __float_as_uint(xv - hif);
          XB[(tt + 1) & 1][m * XSTR + ii] = (unsigned short)(u >> 16);
          XB[(tt + 1) & 1][m * XSTR + 4 + ii] = (unsigned short)(u >> 16);
          XB[(tt + 1) & 1][m * XSTR + 8 + ii] = (unsigned short)(ul >> 16);
        }
      }
      __syncthreads();  // barrier 1-per-iter, matched with L2 branch
    }
  } else {
    // ==================== LAYER-2 WAVES (4..7) ====================
    const int w2 = w - 4;
    const int j = w2 * 16 + l;
    short8 B2h[4][4], B2l[4][4];  // [0..1]=Wih1, [2..3]=Whh1
    floatx4 bias1v[4];
#pragma unroll
    for (int g = 0; g < 4; ++g) {
#pragma unroll
      for (int hf = 0; hf < 2; ++hf) {
        B2h[g][hf]     = wf[OFF_IH1H + (g * 2 + hf) * 256 + w2 * 64 + lane];
        B2l[g][hf]     = wf[OFF_IH1L + (g * 2 + hf) * 256 + w2 * 64 + lane];
        B2h[g][2 + hf] = wf[OFF_HH1H + (g * 2 + hf) * 256 + w2 * 64 + lane];
        B2l[g][2 + hf] = wf[OFF_HH1L + (g * 2 + hf) * 256 + w2 * 64 + lane];
      }
      float bb = b1[g * 64 + j] * ((g == 2) ? SC_TANH : SC_SIG);
      bias1v[g] = (floatx4){bb, bb, bb, bb};
    }
    float c2[16];
#pragma unroll
    for (int k = 0; k < 16; ++k) c2[k] = 0.f;

#pragma unroll 1
    for (int tt = 0; tt < T_ + 1; ++tt) {
      if (tt >= 1) {
        const int t2 = tt - 1;   // computing h2(t2)
        const int p2 = t2 & 1;   // read h1(t2) <- H1*[p2], h2(t2-1) <- H2*[p2^1]
        const bool do_out = (t2 % 5 == 4);
        const int kk = t2 / 5;
#pragma unroll
        for (int mt = 0; mt < 4; ++mt) {
          const int row = mt * 16 + l;
          short8 n0h = *(const short8*)&H1h[p2][row * HSTR + q * 8];
          short8 n1h = *(const short8*)&H1h[p2][row * HSTR + 32 + q * 8];
          short8 n0l = *(const short8*)&H1l[p2][row * HSTR + q * 8];
          short8 n1l = *(const short8*)&H1l[p2][row * HSTR + 32 + q * 8];
          short8 m0h = *(const short8*)&H2h[p2 ^ 1][row * HSTR + q * 8];
          short8 m1h = *(const short8*)&H2h[p2 ^ 1][row * HSTR + 32 + q * 8];
          short8 m0l = *(const short8*)&H2l[p2 ^ 1][row * HSTR + q * 8];
          short8 m1l = *(const short8*)&H2l[p2 ^ 1][row * HSTR + 32 + q * 8];
          floatx4 zs[4];
#pragma unroll
          for (int g = 0; g < 4; ++g) {
            floatx4 a_ = bias1v[g];
            a_ = __builtin_amdgcn_mfma_f32_16x16x32_bf16(n0h, B2h[g][0], a_, 0, 0, 0);
            a_ = __builtin_amdgcn_mfma_f32_16x16x32_bf16(n1h, B2h[g][1], a_, 0, 0, 0);
            a_ = __builtin_amdgcn_mfma_f32_16x16x32_bf16(n0h, B2l[g][0], a_, 0, 0, 0);
            a_ = __builtin_amdgcn_mfma_f32_16x16x32_bf16(n1h, B2l[g][1], a_, 0, 0, 0);
            a_ = __builtin_amdgcn_mfma_f32_16x16x32_bf16(n0l, B2h[g][0], a_, 0, 0, 0);
            a_ = __builtin_amdgcn_mfma_f32_16x16x32_bf16(n1l, B2h[g][1], a_, 0, 0, 0);
            a_ = __builtin_amdgcn_mfma_f32_16x16x32_bf16(m0h, B2h[g][2], a_, 0, 0, 0);
            a_ = __builtin_amdgcn_mfma_f32_16x16x32_bf16(m1h, B2h[g][3], a_, 0, 0, 0);
            a_ = __builtin_amdgcn_mfma_f32_16x16x32_bf16(m0h, B2l[g][2], a_, 0, 0, 0);
            a_ = __builtin_amdgcn_mfma_f32_16x16x32_bf16(m1h, B2l[g][3], a_, 0, 0, 0);
            a_ = __builtin_amdgcn_mfma_f32_16x16x32_bf16(m0l, B2h[g][2], a_, 0, 0, 0);
            a_ = __builtin_amdgcn_mfma_f32_16x16x32_bf16(m1l, B2h[g][3], a_, 0, 0, 0);
            zs[g] = a_;
          }
#pragma unroll
          for (int r = 0; r < 4; ++r) {
            float si = sigm2_(zs[0][r]);
            float sf = sigm2_(zs[1][r]);
            float tg = tanhg_(zs[2][r]);
            float so = sigm2_(zs[3][r]);
            float cc = sf * c2[mt * 4 + r] + si * tg;
            c2[mt * 4 + r] = cc;
            float h = so * tanhc_(cc);
            unsigned u = __float_as_uint(h);
            float hif = __uint_as_float(u & 0xffff0000u);
            unsigned ul = __float_as_uint(h - hif);
            const int m = mt * 16 + q * 4 + r;
            H2h[p2][m * HSTR + j] = (unsigned short)(u >> 16);
            H2l[p2][m * HSTR + j] = (unsigned short)(ul >> 16);
            if (do_out) out[(size_t)(mbase + m) * 320 + (size_t)kk * 64 + j] = h;
          }
        }
      }
      __syncthreads();  // matched with L1 branch
    }
  }
}

extern "C" void kernel_launch(void* const* d_in, const int* in_sizes, int n_in,
                              void* d_out, int out_size, void* d_ws, size_t ws_size,
                              hipStream_t stream) {
  const float* xp   = (const float*)d_in[0];
  const float* Wih0 = (const float*)d_in[1];
  const float* Whh0 = (const float*)d_in[2];
  const float* b0   = (const float*)d_in[3];
  const float* Wih1 = (const float*)d_in[4];
  const float* Whh1 = (const float*)d_in[5];
  const float* b1   = (const float*)d_in[6];
  float* outp = (float*)d_out;
  unsigned short* ws = (unsigned short*)d_ws;

  // Pre-scale + pre-split weights into fragment-ordered hi/lo arrays.
  hipLaunchKernelGGL(prep_weights, dim3(28), dim3(256), 0, stream,
                     Wih0, Whh0, Wih1, Whh1, ws);

  const int B = in_sizes[0] / (T_ * I_);  // 65536
  dim3 grid(B / MB), block(512);
  hipLaunchKernelGGL(lstm2_kernel, grid, block, 0, stream,
                     xp, b0, b1, (const short8*)ws, outp);
}

// Round 6
// 566.616 us; speedup vs baseline: 1.0679x; 1.0306x over previous
//
#include <hip/hip_runtime.h>
#include <hip/hip_bf16.h>

// LSTMEncoder: B=65536, T=25, I=4, H=64, 2 layers, out = h2 at t=4,9,14,19,24.
// Split-precision matmul (v = hi + lo bf16 pairs) for f32-accurate trajectory:
//   h@W ~= h_hi@W_hi + h_hi@W_lo + h_lo@W_hi  (exact products, f32 MFMA acc)
// Elementwise pure f32 (hw exp2/rcp).
//
// R7:  wave specialization (waves 0-3 = layer 1, 4-7 = layer 2), 1 barrier/iter.
// R8:  pre-split weights into d_ws (killed per-iter splitf remat).
// R9/R10: LDS squeeze; occupancy structurally capped at 2 waves/SIMD by
//   register-resident weights (~208 regs/SIMD across the L1+L2 wave pair).
// R11: anti-phase wave scheduling: null. R12: ew VALU cut (VALUBusy 56->46):
//   null on time. Conclusion: neither pipe throughput nor wave phasing binds.
// R13 (this round): BREAK THE DEPENDENT MFMA RUNS. MfmaUtil 40% x 13,270
//   cyc/iter / 304 MFMAs = 17.4 cyc/MFMA = the DEPENDENT-issue latency of
//   mfma 16x16x32 (throughput is 4.85) -> compiler emitted each gate's
//   accumulator chain back-to-back (gate-major), stalling full latency per
//   MFMA. Rewrite term-major: each round issues one MFMA of each of the 4
//   independent gate chains (a0..a3), so same-chain issues are ~19 cyc apart
//   >= latency. Enforced with sched_group_barrier(MFMA,4,0) per round (data
//   deps make each group exactly one-per-gate). Per-gate accumulation order
//   is UNCHANGED -> bit-identical output (absmax tripwire: 4.882812e-4).
//
// MFMA 16x16x32 bf16 layouts (measured, learn_hip m89/m120):
//   A[m][k]: m=lane&15, k=(lane>>4)*8+e ; B[k][n]: n=lane&15, k=(lane>>4)*8+e
//   C/D    : col=lane&15, row=(lane>>4)*4+reg

typedef short short8 __attribute__((ext_vector_type(8)));
typedef float floatx4 __attribute__((ext_vector_type(4)));

namespace {
constexpr int T_ = 25;
constexpr int I_ = 4;
constexpr int MB = 64;     // batch rows per block
constexpr int HSTR = 72;   // LDS row stride (shorts): 144B, 16B-aligned, 2-way banks
constexpr int XSTR = 24;   // x tile stride (shorts): 48B, 2-way banks
constexpr int XPAD = 8;    // last-row overread pad (q=3 reads offs 24..31)

// Workspace layout, in short8 (16B fragment-row) units.
constexpr int OFF_BX   = 0;
constexpr int OFF_HH0H = 1024;
constexpr int OFF_HH0L = 3072;
constexpr int OFF_IH1H = 5120;
constexpr int OFF_IH1L = 7168;
constexpr int OFF_HH1H = 9216;
constexpr int OFF_HH1L = 11264;

constexpr float SC_SIG  = -1.44269504088896340736f;  // -log2(e)
constexpr float SC_TANH = -2.88539008177792681472f;  // -2*log2(e)
}

// Activation helpers. Inputs of sigm2_/tanhg_ are PRE-SCALED via the weights.
__device__ __forceinline__ float sigm2_(float z) {   // z = -log2e * x
  float t = __builtin_amdgcn_exp2f(z);
  return __builtin_amdgcn_rcpf(1.0f + t);
}
__device__ __forceinline__ float tanhg_(float z) {   // z = -2*log2e * x
  float t = __builtin_amdgcn_exp2f(z);
  return 2.0f * __builtin_amdgcn_rcpf(1.0f + t) - 1.0f;
}
__device__ __forceinline__ float tanhc_(float x) {   // plain tanh (c is unscaled)
  float t = __builtin_amdgcn_exp2f(x * SC_TANH);
  return 2.0f * __builtin_amdgcn_rcpf(1.0f + t) - 1.0f;
}

__device__ __forceinline__ unsigned short f2bf_(float f) {  // RNE f32->bf16 (prep only)
  unsigned u = __float_as_uint(f);
  u += 0x7FFFu + ((u >> 16) & 1u);
  return (unsigned short)(u >> 16);
}
__device__ __forceinline__ float bf2f_(unsigned short s) {
  return __uint_as_float(((unsigned)s) << 16);
}
__device__ __forceinline__ void splitf_(float f, unsigned short& hi, unsigned short& lo) {
  hi = f2bf_(f);
  lo = f2bf_(f - bf2f_(hi));
}

// ---------------------------------------------------------------------------
// Prep kernel: scale by activation constants, then split into fragment-ordered
// hi/lo short8 rows. Runs once; RNE split kept here (free).
// ---------------------------------------------------------------------------
__global__ void prep_weights(const float* __restrict__ Wih0,   // [256,4]
                             const float* __restrict__ Whh0,   // [256,64]
                             const float* __restrict__ Wih1,   // [256,64]
                             const float* __restrict__ Whh1,   // [256,64]
                             unsigned short* __restrict__ ws) {
  const int t = blockIdx.x * 256 + threadIdx.x;
  if (t < 1024) {
    const int lane = t & 63, w = (t >> 6) & 3, g = t >> 8;
    const int l = lane & 15, q = lane >> 4;
    const int n = g * 64 + w * 16 + l;
    const float sc = (g == 2) ? SC_TANH : SC_SIG;
    unsigned short row[8];
#pragma unroll
    for (int e = 0; e < 8; ++e) row[e] = 0;
    if (q < 2) {
#pragma unroll
      for (int e = 0; e < 4; ++e) {
        unsigned short h, lo;
        splitf_(Wih0[n * 4 + e] * sc, h, lo);
        row[e] = h;
        if (q == 0) row[4 + e] = lo;
      }
    }
#pragma unroll
    for (int e = 0; e < 8; ++e) ws[(OFF_BX + t) * 8 + e] = row[e];
  } else if (t < 7168) {
    const int a = (t - 1024) >> 11;    // 0:Whh0 1:Wih1 2:Whh1
    const int r = (t - 1024) & 2047;   // r = g*512 + hf*256 + w*64 + lane
    const int lane = r & 63, w = (r >> 6) & 3, hf = (r >> 8) & 1, g = r >> 9;
    const int l = lane & 15, q = lane >> 4;
    const int n = g * 64 + w * 16 + l;
    const float sc = (g == 2) ? SC_TANH : SC_SIG;
    const float* src = (a == 0) ? Whh0 : (a == 1) ? Wih1 : Whh1;
    const int offH = (a == 0) ? OFF_HH0H : (a == 1) ? OFF_IH1H : OFF_HH1H;
    const int offL = offH + 2048;
#pragma unroll
    for (int e = 0; e < 8; ++e) {
      unsigned short h, lo;
      splitf_(src[n * 64 + hf * 32 + q * 8 + e] * sc, h, lo);
      ws[(offH + r) * 8 + e] = h;
      ws[(offL + r) * 8 + e] = lo;
    }
  }
}

// Term-major round: one MFMA from each of the 4 independent gate chains.
// Data deps (a0..a3 accumulate) + the MFMA sched group force round-robin.
#define R4(A_, b0_, b1_, b2_, b3_)                                           \
  a0 = __builtin_amdgcn_mfma_f32_16x16x32_bf16((A_), (b0_), a0, 0, 0, 0);    \
  a1 = __builtin_amdgcn_mfma_f32_16x16x32_bf16((A_), (b1_), a1, 0, 0, 0);    \
  a2 = __builtin_amdgcn_mfma_f32_16x16x32_bf16((A_), (b2_), a2, 0, 0, 0);    \
  a3 = __builtin_amdgcn_mfma_f32_16x16x32_bf16((A_), (b3_), a3, 0, 0, 0);    \
  __builtin_amdgcn_sched_group_barrier(0x008, 4, 0);

// ---------------------------------------------------------------------------
// Main kernel
// ---------------------------------------------------------------------------
__global__ __launch_bounds__(512, 2)
void lstm2_kernel(const float* __restrict__ x,     // [B,25,4]
                  const float* __restrict__ b0,    // [256]
                  const float* __restrict__ b1,    // [256]
                  const short8* __restrict__ wf,   // pre-split scaled weight frags
                  float* __restrict__ out) {       // [B,5,64]
  // h1(t) lives in H1*[t&1]; h2(t) in H2*[t&1]; x(t) in XB[t&1].
  __shared__ __align__(16) unsigned short H1h[2][MB * HSTR];
  __shared__ __align__(16) unsigned short H1l[2][MB * HSTR];
  __shared__ __align__(16) unsigned short H2h[2][MB * HSTR];
  __shared__ __align__(16) unsigned short H2l[2][MB * HSTR];
  __shared__ __align__(16) unsigned short XB[2][MB * XSTR + XPAD];

  const int tid = threadIdx.x;
  const int lane = tid & 63;
  const int w = tid >> 6;   // 0..7
  const int l = lane & 15;
  const int q = lane >> 4;
  const int mbase = blockIdx.x * MB;

  // ---- init LDS: zero the [1] state buffers (h(-1)=0) + both XB buffers ----
  for (int idx = tid; idx < MB * 64; idx += 512) {
    int m = idx >> 6, k = idx & 63;
    H1h[1][m * HSTR + k] = 0;
    H1l[1][m * HSTR + k] = 0;
    H2h[1][m * HSTR + k] = 0;
    H2l[1][m * HSTR + k] = 0;
  }
  for (int idx = tid; idx < 2 * (MB * XSTR + XPAD); idx += 512) (&XB[0][0])[idx] = 0;
  if (tid < 256) {  // stage x(0) into XB[0] (truncation split)
    int m = tid >> 2, ii = tid & 3;
    float xv = x[(mbase + m) * (T_ * I_) + ii];
    unsigned u = __float_as_uint(xv);
    float hif = __uint_as_float(u & 0xffff0000u);
    unsigned ul = __float_as_uint(xv - hif);
    XB[0][m * XSTR + ii] = (unsigned short)(u >> 16);
    XB[0][m * XSTR + 4 + ii] = (unsigned short)(u >> 16);
    XB[0][m * XSTR + 8 + ii] = (unsigned short)(ul >> 16);
  }
  __syncthreads();

  if (w < 4) {
    // ==================== LAYER-1 WAVES (0..3) ====================
    const int j = w * 16 + l;  // hidden col owned (all 4 gates)
    short8 B1h[4][2], B1l[4][2], BXf[4];
    floatx4 bias0v[4];
#pragma unroll
    for (int g = 0; g < 4; ++g) {
      BXf[g] = wf[OFF_BX + g * 256 + w * 64 + lane];
#pragma unroll
      for (int hf = 0; hf < 2; ++hf) {
        B1h[g][hf] = wf[OFF_HH0H + (g * 2 + hf) * 256 + w * 64 + lane];
        B1l[g][hf] = wf[OFF_HH0L + (g * 2 + hf) * 256 + w * 64 + lane];
      }
      float bb = b0[g * 64 + j] * ((g == 2) ? SC_TANH : SC_SIG);
      bias0v[g] = (floatx4){bb, bb, bb, bb};
    }
    float c1[16];
#pragma unroll
    for (int k = 0; k < 16; ++k) c1[k] = 0.f;

#pragma unroll 1
    for (int tt = 0; tt < T_ + 1; ++tt) {
      if (tt < T_) {
        const int p = tt & 1;  // write h1(tt) -> H1*[p]; read h1(tt-1) <- H1*[p^1]
#pragma unroll
        for (int mt = 0; mt < 4; ++mt) {
          const int row = mt * 16 + l;
          short8 a0h = *(const short8*)&H1h[p ^ 1][row * HSTR + q * 8];
          short8 a1h = *(const short8*)&H1h[p ^ 1][row * HSTR + 32 + q * 8];
          short8 a0l = *(const short8*)&H1l[p ^ 1][row * HSTR + q * 8];
          short8 a1l = *(const short8*)&H1l[p ^ 1][row * HSTR + 32 + q * 8];
          short8 ax  = *(const short8*)&XB[p][row * XSTR + q * 8];
          floatx4 a0 = bias0v[0], a1 = bias0v[1], a2 = bias0v[2], a3 = bias0v[3];
          // 7 term-major rounds; per-gate order identical to the old chain:
          // BX, B1h[.][0], B1h[.][1], B1l[.][0], B1l[.][1], (lo)B1h[.][0], (lo)B1h[.][1]
          R4(ax,  BXf[0],     BXf[1],     BXf[2],     BXf[3])
          R4(a0h, B1h[0][0],  B1h[1][0],  B1h[2][0],  B1h[3][0])
          R4(a1h, B1h[0][1],  B1h[1][1],  B1h[2][1],  B1h[3][1])
          R4(a0h, B1l[0][0],  B1l[1][0],  B1l[2][0],  B1l[3][0])
          R4(a1h, B1l[0][1],  B1l[1][1],  B1l[2][1],  B1l[3][1])
          R4(a0l, B1h[0][0],  B1h[1][0],  B1h[2][0],  B1h[3][0])
          R4(a1l, B1h[0][1],  B1h[1][1],  B1h[2][1],  B1h[3][1])
#pragma unroll
          for (int r = 0; r < 4; ++r) {
            float si = sigm2_(a0[r]);
            float sf = sigm2_(a1[r]);
            float tg = tanhg_(a2[r]);
            float so = sigm2_(a3[r]);
            float cc = sf * c1[mt * 4 + r] + si * tg;
            c1[mt * 4 + r] = cc;
            float h = so * tanhc_(cc);
            unsigned u = __float_as_uint(h);
            float hif = __uint_as_float(u & 0xffff0000u);
            unsigned ul = __float_as_uint(h - hif);
            const int m = mt * 16 + q * 4 + r;
            H1h[p][m * HSTR + j] = (unsigned short)(u >> 16);
            H1l[p][m * HSTR + j] = (unsigned short)(ul >> 16);
          }
        }
        if (tt + 1 < T_) {  // stage x(tt+1) into the other XB buffer
          int m = (tid & 255) >> 2, ii = tid & 3;
          float xv = x[(mbase + m) * (T_ * I_) + (tt + 1) * I_ + ii];
          unsigned u = __float_as_uint(xv);
          float hif = __uint_as_float(u & 0xffff0000u);
          unsigned ul = __float_as_uint(xv - hif);
          XB[(tt + 1) & 1][m * XSTR + ii] = (unsigned short)(u >> 16);
          XB[(tt + 1) & 1][m * XSTR + 4 + ii] = (unsigned short)(u >> 16);
          XB[(tt + 1) & 1][m * XSTR + 8 + ii] = (unsigned short)(ul >> 16);
        }
      }
      __syncthreads();  // barrier 1-per-iter, matched with L2 branch
    }
  } else {
    // ==================== LAYER-2 WAVES (4..7) ====================
    const int w2 = w - 4;
    const int j = w2 * 16 + l;
    short8 B2h[4][4], B2l[4][4];  // [0..1]=Wih1, [2..3]=Whh1
    floatx4 bias1v[4];
#pragma unroll
    for (int g = 0; g < 4; ++g) {
#pragma unroll
      for (int hf = 0; hf < 2; ++hf) {
        B2h[g][hf]     = wf[OFF_IH1H + (g * 2 + hf) * 256 + w2 * 64 + lane];
        B2l[g][hf]     = wf[OFF_IH1L + (g * 2 + hf) * 256 + w2 * 64 + lane];
        B2h[g][2 + hf] = wf[OFF_HH1H + (g * 2 + hf) * 256 + w2 * 64 + lane];
        B2l[g][2 + hf] = wf[OFF_HH1L + (g * 2 + hf) * 256 + w2 * 64 + lane];
      }
      float bb = b1[g * 64 + j] * ((g == 2) ? SC_TANH : SC_SIG);
      bias1v[g] = (floatx4){bb, bb, bb, bb};
    }
    float c2[16];
#pragma unroll
    for (int k = 0; k < 16; ++k) c2[k] = 0.f;

#pragma unroll 1
    for (int tt = 0; tt < T_ + 1; ++tt) {
      if (tt >= 1) {
        const int t2 = tt - 1;   // computing h2(t2)
        const int p2 = t2 & 1;   // read h1(t2) <- H1*[p2], h2(t2-1) <- H2*[p2^1]
        const bool do_out = (t2 % 5 == 4);
        const int kk = t2 / 5;
#pragma unroll
        for (int mt = 0; mt < 4; ++mt) {
          const int row = mt * 16 + l;
          short8 n0h = *(const short8*)&H1h[p2][row * HSTR + q * 8];
          short8 n1h = *(const short8*)&H1h[p2][row * HSTR + 32 + q * 8];
          short8 n0l = *(const short8*)&H1l[p2][row * HSTR + q * 8];
          short8 n1l = *(const short8*)&H1l[p2][row * HSTR + 32 + q * 8];
          short8 m0h = *(const short8*)&H2h[p2 ^ 1][row * HSTR + q * 8];
          short8 m1h = *(const short8*)&H2h[p2 ^ 1][row * HSTR + 32 + q * 8];
          short8 m0l = *(const short8*)&H2l[p2 ^ 1][row * HSTR + q * 8];
          short8 m1l = *(const short8*)&H2l[p2 ^ 1][row * HSTR + 32 + q * 8];
          floatx4 a0 = bias1v[0], a1 = bias1v[1], a2 = bias1v[2], a3 = bias1v[3];
          // 12 term-major rounds; per-gate order identical to the old chain.
          R4(n0h, B2h[0][0], B2h[1][0], B2h[2][0], B2h[3][0])
          R4(n1h, B2h[0][1], B2h[1][1], B2h[2][1], B2h[3][1])
          R4(n0h, B2l[0][0], B2l[1][0], B2l[2][0], B2l[3][0])
          R4(n1h, B2l[0][1], B2l[1][1], B2l[2][1], B2l[3][1])
          R4(n0l, B2h[0][0], B2h[1][0], B2h[2][0], B2h[3][0])
          R4(n1l, B2h[0][1], B2h[1][1], B2h[2][1], B2h[3][1])
          R4(m0h, B2h[0][2], B2h[1][2], B2h[2][2], B2h[3][2])
          R4(m1h, B2h[0][3], B2h[1][3], B2h[2][3], B2h[3][3])
          R4(m0h, B2l[0][2], B2l[1][2], B2l[2][2], B2l[3][2])
          R4(m1h, B2l[0][3], B2l[1][3], B2l[2][3], B2l[3][3])
          R4(m0l, B2h[0][2], B2h[1][2], B2h[2][2], B2h[3][2])
          R4(m1l, B2h[0][3], B2h[1][3], B2h[2][3], B2h[3][3])
#pragma unroll
          for (int r = 0; r < 4; ++r) {
            float si = sigm2_(a0[r]);
            float sf = sigm2_(a1[r]);
            float tg = tanhg_(a2[r]);
            float so = sigm2_(a3[r]);
            float cc = sf * c2[mt * 4 + r] + si * tg;
            c2[mt * 4 + r] = cc;
            float h = so * tanhc_(cc);
            unsigned u = __float_as_uint(h);
            float hif = __uint_as_float(u & 0xffff0000u);
            unsigned ul = __float_as_uint(h - hif);
            const int m = mt * 16 + q * 4 + r;
            H2h[p2][m * HSTR + j] = (unsigned short)(u >> 16);
            H2l[p2][m * HSTR + j] = (unsigned short)(ul >> 16);
            if (do_out) out[(size_t)(mbase + m) * 320 + (size_t)kk * 64 + j] = h;
          }
        }
      }
      __syncthreads();  // matched with L1 branch
    }
  }
}

#undef R4

extern "C" void kernel_launch(void* const* d_in, const int* in_sizes, int n_in,
                              void* d_out, int out_size, void* d_ws, size_t ws_size,
                              hipStream_t stream) {
  const float* xp   = (const float*)d_in[0];
  const float* Wih0 = (const float*)d_in[1];
  const float* Whh0 = (const float*)d_in[2];
  const float* b0   = (const float*)d_in[3];
  const float* Wih1 = (const float*)d_in[4];
  const float* Whh1 = (const float*)d_in[5];
  const float* b1   = (const float*)d_in[6];
  float* outp = (float*)d_out;
  unsigned short* ws = (unsigned short*)d_ws;

  // Pre-scale + pre-split weights into fragment-ordered hi/lo arrays.
  hipLaunchKernelGGL(prep_weights, dim3(28), dim3(256), 0, stream,
                     Wih0, Whh0, Wih1, Whh1, ws);

  const int B = in_sizes[0] / (T_ * I_);  // 65536
  dim3 grid(B / MB), block(512);
  hipLaunchKernelGGL(lstm2_kernel, grid, block, 0, stream,
                     xp, b0, b1, (const short8*)ws, outp);
}